// Round 9
// baseline (503.465 us; speedup 1.0000x reference)
//
#include <hip/hip_runtime.h>
#include <hip/hip_bf16.h>

typedef __bf16 bf16;
typedef bf16 bf16x8 __attribute__((ext_vector_type(8)));
typedef bf16 bf16x4 __attribute__((ext_vector_type(4)));
typedef short s16x4 __attribute__((ext_vector_type(4)));
typedef float f32x4 __attribute__((ext_vector_type(4)));

#define SCALE 0.17677669529663687f  // 1/sqrt(32)

// LDS: двdouble-buffered xb bf16 [64][208] = 2 x 26,624 B = 53,248 B -> 2 blocks/CU.
#define XSTR 208
#define XELEMS 13312
#define SMEM_ELEMS 26624

#if defined(__has_builtin)
#if __has_builtin(__builtin_amdgcn_mfma_f32_16x16x16bf16_1k)
#define HAS_MFMA16 1
#endif
#endif

// ---------------- prep kernel (unchanged, validated) ----------------
__global__ void wattn_prep(const float* __restrict__ wq, const float* __restrict__ wkv,
                           const float* __restrict__ bias_table, const float* __restrict__ proj_w,
                           bf16* __restrict__ wqkvT, bf16* __restrict__ projT,
                           float* __restrict__ biasB)
{
    int t = blockIdx.x * 256 + threadIdx.x;
    if (t < 110592) {                       // wqkvT[n][k] = W[k][n]
        int n = t / 192, k = t % 192;
        float v = (n < 192) ? wq[k * 192 + n] : wkv[k * 384 + (n - 192)];
        wqkvT[t] = (bf16)v;
    } else if (t < 147456) {                // projT[n][k] = proj_w[k][n]
        int e = t - 110592;
        int n = e / 192, k = e % 192;
        projT[e] = (bf16)proj_w[k * 192 + n];
    } else if (t < 172032) {                // biasB[h][m>>2][n][m&3]
        int e = t - 147456;
        int h  = e >> 12;
        int mb = (e >> 8) & 15;
        int n  = (e >> 2) & 63;
        int mr = e & 3;
        int m  = mb * 4 + mr;
        int idx = ((n & 7) - (m & 7) + 7) * 15 + ((n >> 3) - (m >> 3) + 7);
        biasB[e] = bias_table[idx * 6 + h];
    }
}

#if !defined(HAS_MFMA16)
// fallback: build K=32 frag from two D-layout bf16x4 tiles via shuffles
__device__ __forceinline__ bf16x8 build8(bf16x4 t0, bf16x4 t1, int li, int gi) {
    union { bf16x4 v; unsigned u[2]; } a0, a1;
    a0.v = t0; a1.v = t1;
    int b = li + 32 * (gi & 1);
    unsigned l0  = __shfl(a0.u[0], b),      l1  = __shfl(a0.u[1], b);
    unsigned l0h = __shfl(a0.u[0], b + 16), l1h = __shfl(a0.u[1], b + 16);
    unsigned h0  = __shfl(a1.u[0], b),      h1  = __shfl(a1.u[1], b);
    unsigned h0h = __shfl(a1.u[0], b + 16), h1h = __shfl(a1.u[1], b + 16);
    bool hi = (gi & 2);
    union { bf16x8 v8; unsigned u[4]; } r;
    r.u[0] = hi ? h0 : l0;   r.u[1] = hi ? h1 : l1;
    r.u[2] = hi ? h0h : l0h; r.u[3] = hi ? h1h : l1h;
    return r.v8;
}
#endif

// ---------------- fused main kernel: TWO windows per block (pipelined), one head per wave ----
// Per window: passA(q,k) -> QK^T -> softmax -> passB(v) -> [issue next-window loads] -> PV ->
// B -> attn-out + [stage-write next window] -> C -> proj -> full-line stores.
// 2.5 barriers/window; stage HBM latency fully hidden under PV/attn-out.
__global__ __launch_bounds__(384, 4)
void wattn_main(const float* __restrict__ x, const bf16* __restrict__ wqkvT,
                const float* __restrict__ bq, const float* __restrict__ bkv,
                const bf16* __restrict__ projT, const float* __restrict__ biasB,
                const float* __restrict__ proj_b, float* __restrict__ outg, int B)
{
    __shared__ __align__(16) bf16 smem[SMEM_ELEMS];
    const int tid = threadIdx.x;
    const int li  = tid & 15;
    const int gi  = (tid >> 4) & 3;
    const int w   = tid >> 6;        // wave = head, 0..5
    const int win0 = blockIdx.x * 2;
    if (win0 >= B) return;

    const int srow = tid / 48, scol = tid % 48;
    const f32x4 fz = {0.f, 0.f, 0.f, 0.f};

    // ---- stage window 0: f32 global -> bf16 LDS buffer 0 ----
    {
        const float4* xg = (const float4*)(x + (size_t)win0 * 12288);
#pragma unroll
        for (int t = 0; t < 8; ++t) {
            float4 p = xg[(srow + 8 * t) * 48 + scol];
            bf16x4 v; v[0]=(bf16)p.x; v[1]=(bf16)p.y; v[2]=(bf16)p.z; v[3]=(bf16)p.w;
            *(bf16x4*)&smem[(srow + 8 * t) * XSTR + scol * 4] = v;
        }
    }
    __syncthreads();

    int cur = 0;
#pragma unroll 1
    for (int i = 0; i < 2; ++i) {
        const int win = win0 + i;
        if (win >= B) break;
        bf16* xb = smem + cur * XELEMS;
        const bool pf = (i == 0) && (win0 + 1 < B);

        // ======== pass A: q,k via TRANSPOSED GEMM; bias as accumulator C-init ========
        bf16x4 qf[2][4], kf[2][4];
        {
            f32x4 bjq0 = *(const f32x4*)&bq [32 * w + 4 * gi];
            f32x4 bjq1 = *(const f32x4*)&bq [32 * w + 16 + 4 * gi];
            f32x4 bjk0 = *(const f32x4*)&bkv[32 * w + 4 * gi];
            f32x4 bjk1 = *(const f32x4*)&bkv[32 * w + 16 + 4 * gi];
            f32x4 aqk[4][4];
#pragma unroll
            for (int c = 0; c < 4; ++c) {
                aqk[0][c] = bjq0; aqk[1][c] = bjq1;
                aqk[2][c] = bjk0; aqk[3][c] = bjk1;
            }
            __builtin_amdgcn_s_setprio(1);
#pragma unroll 2
            for (int kk = 0; kk < 6; ++kk) {
                bf16x8 bx[4], aw[4];
#pragma unroll
                for (int c = 0; c < 4; ++c)
                    bx[c] = *(const bf16x8*)&xb[(c * 16 + li) * XSTR + kk * 32 + gi * 8];
#pragma unroll
                for (int j = 0; j < 4; ++j) {
                    int T = (j < 2) ? (2 * w + j) : (12 + 2 * w + (j - 2));
                    aw[j] = *(const bf16x8*)&wqkvT[(size_t)(T * 16 + li) * 192 + kk * 32 + gi * 8];
                }
#pragma unroll
                for (int j = 0; j < 4; ++j)
#pragma unroll
                    for (int c = 0; c < 4; ++c)
                        aqk[j][c] = __builtin_amdgcn_mfma_f32_16x16x32_bf16(aw[j], bx[c], aqk[j][c], 0, 0, 0);
            }
            __builtin_amdgcn_s_setprio(0);
            // epilogue A: leaky (+SCALE for q) -> registers
#pragma unroll
            for (int j = 0; j < 2; ++j)
#pragma unroll
                for (int c = 0; c < 4; ++c) {
                    bf16x4 rq, rk;
#pragma unroll
                    for (int rg = 0; rg < 4; ++rg) {
                        float tq = aqk[j][c][rg];
                        float tk = aqk[2 + j][c][rg];
                        tq = (fmaxf(tq, 0.f) + 0.2f * fminf(tq, 0.f)) * SCALE;
                        tk =  fmaxf(tk, 0.f) + 0.2f * fminf(tk, 0.f);
                        rq[rg] = (bf16)tq;
                        rk[rg] = (bf16)tk;
                    }
                    qf[j][c] = rq;
                    kf[j][c] = rk;
                }
        }

        // ======== QK^T from registers, rel-pos-bias as C-init ========
        f32x4 s[4][4];
        __builtin_amdgcn_s_setprio(1);
#pragma unroll
        for (int cm = 0; cm < 4; ++cm)
#pragma unroll
            for (int cn = 0; cn < 4; ++cn) {
                f32x4 bv = *(const f32x4*)&biasB[w * 4096 + (4 * cm + gi) * 256 + (16 * cn + li) * 4];
#if defined(HAS_MFMA16)
                f32x4 t = __builtin_amdgcn_mfma_f32_16x16x16bf16_1k(
                    __builtin_bit_cast(s16x4, kf[0][cm]), __builtin_bit_cast(s16x4, qf[0][cn]), bv, 0, 0, 0);
                s[cm][cn] = __builtin_amdgcn_mfma_f32_16x16x16bf16_1k(
                    __builtin_bit_cast(s16x4, kf[1][cm]), __builtin_bit_cast(s16x4, qf[1][cn]), t, 0, 0, 0);
#else
                s[cm][cn] = __builtin_amdgcn_mfma_f32_16x16x32_bf16(
                    build8(kf[0][cm], kf[1][cm], li, gi), build8(qf[0][cn], qf[1][cn], li, gi), bv, 0, 0, 0);
#endif
            }
        __builtin_amdgcn_s_setprio(0);

        // ======== softmax over keys; s dies into pb ========
        float rs[4];
        bf16x4 pb[4][4];
#pragma unroll
        for (int cn = 0; cn < 4; ++cn) {
            float m_ = -1e30f;
#pragma unroll
            for (int cm = 0; cm < 4; ++cm)
#pragma unroll
                for (int rg = 0; rg < 4; ++rg) m_ = fmaxf(m_, s[cm][cn][rg]);
            m_ = fmaxf(m_, __shfl_xor(m_, 16));
            m_ = fmaxf(m_, __shfl_xor(m_, 32));
            float ss = 0.f;
#pragma unroll
            for (int cm = 0; cm < 4; ++cm) {
                bf16x4 r;
#pragma unroll
                for (int rg = 0; rg < 4; ++rg) {
                    float p = __expf(s[cm][cn][rg] - m_);
                    ss += p;
                    r[rg] = (bf16)p;
                }
                pb[cm][cn] = r;
            }
            ss += __shfl_xor(ss, 16);
            ss += __shfl_xor(ss, 32);
            rs[cn] = 1.f / ss;
        }

        // ======== pass B: v via NORMAL GEMM; bias as C-init ========
        bf16x4 vf[2][4];   // [d-half][m-subtile]
        {
            f32x4 bjv0 = *(const f32x4*)&bkv[192 + 32 * w + 4 * gi];
            f32x4 bjv1 = *(const f32x4*)&bkv[192 + 32 * w + 16 + 4 * gi];
            f32x4 av_[4][2];
#pragma unroll
            for (int rt = 0; rt < 4; ++rt) { av_[rt][0] = bjv0; av_[rt][1] = bjv1; }
            __builtin_amdgcn_s_setprio(1);
#pragma unroll 2
            for (int kk = 0; kk < 6; ++kk) {
                bf16x8 a[4], bwv[2];
#pragma unroll
                for (int rt = 0; rt < 4; ++rt)
                    a[rt] = *(const bf16x8*)&xb[(rt * 16 + li) * XSTR + kk * 32 + gi * 8];
#pragma unroll
                for (int j = 0; j < 2; ++j)
                    bwv[j] = *(const bf16x8*)&wqkvT[(size_t)((24 + 2 * w + j) * 16 + li) * 192 + kk * 32 + gi * 8];
#pragma unroll
                for (int rt = 0; rt < 4; ++rt)
#pragma unroll
                    for (int j = 0; j < 2; ++j)
                        av_[rt][j] = __builtin_amdgcn_mfma_f32_16x16x32_bf16(a[rt], bwv[j], av_[rt][j], 0, 0, 0);
            }
            __builtin_amdgcn_s_setprio(0);
#pragma unroll
            for (int j = 0; j < 2; ++j)
#pragma unroll
                for (int rt = 0; rt < 4; ++rt) {
                    bf16x4 r;
#pragma unroll
                    for (int rg = 0; rg < 4; ++rg) {
                        float t = av_[rt][j][rg];
                        t = fmaxf(t, 0.f) + 0.2f * fminf(t, 0.f);
                        r[rg] = (bf16)t;
                    }
                    vf[j][rt] = r;
                }
        }

        // ---- issue next-window global loads (T14: hidden under PV + barrier + attn-out) ----
        float4 px[8];
        if (pf) {
            const float4* xg2 = (const float4*)(x + (size_t)(win + 1) * 12288);
#pragma unroll
            for (int t = 0; t < 8; ++t) px[t] = xg2[(srow + 8 * t) * 48 + scol];
        }

        // ======== PV entirely from registers ========
        bf16x4 obf[2][4];
        __builtin_amdgcn_s_setprio(1);
#pragma unroll
        for (int ct = 0; ct < 2; ++ct)
#pragma unroll
            for (int cn = 0; cn < 4; ++cn) {
#if defined(HAS_MFMA16)
                f32x4 t = fz;
#pragma unroll
                for (int rt = 0; rt < 4; ++rt)
                    t = __builtin_amdgcn_mfma_f32_16x16x16bf16_1k(
                            __builtin_bit_cast(s16x4, vf[ct][rt]),
                            __builtin_bit_cast(s16x4, pb[rt][cn]), t, 0, 0, 0);
#else
                f32x4 t = fz;
#pragma unroll
                for (int c = 0; c < 2; ++c)
                    t = __builtin_amdgcn_mfma_f32_16x16x32_bf16(
                            build8(vf[ct][2 * c], vf[ct][2 * c + 1], li, gi),
                            build8(pb[2 * c][cn], pb[2 * c + 1][cn], li, gi), t, 0, 0, 0);
#endif
                bf16x4 r;
#pragma unroll
                for (int rg = 0; rg < 4; ++rg) r[rg] = (bf16)(t[rg] * rs[cn]);
                obf[ct][cn] = r;
            }
        __builtin_amdgcn_s_setprio(0);
        __syncthreads();                                 // B: all xb[cur] reads done

        // attn-out -> xb[cur]
#pragma unroll
        for (int ct = 0; ct < 2; ++ct)
#pragma unroll
            for (int cn = 0; cn < 4; ++cn)
                *(bf16x4*)&xb[(cn * 16 + li) * XSTR + 32 * w + 16 * ct + 4 * gi] = obf[ct][cn];
        // stage-write next window into the other buffer
        if (pf) {
            bf16* xn = smem + (cur ^ 1) * XELEMS;
#pragma unroll
            for (int t = 0; t < 8; ++t) {
                bf16x4 v; v[0]=(bf16)px[t].x; v[1]=(bf16)px[t].y; v[2]=(bf16)px[t].z; v[3]=(bf16)px[t].w;
                *(bf16x4*)&xn[(srow + 8 * t) * XSTR + scol * 4] = v;
            }
        }
        __syncthreads();                                 // C: attn-out ready (+ next stage ready)

        // ======== proj (transposed); proj_b as C-init ========
        f32x4 pa[2][4];
        {
            f32x4 pb0 = *(const f32x4*)&proj_b[32 * w + 4 * gi];
            f32x4 pb1 = *(const f32x4*)&proj_b[32 * w + 16 + 4 * gi];
#pragma unroll
            for (int cn = 0; cn < 4; ++cn) { pa[0][cn] = pb0; pa[1][cn] = pb1; }
        }
        __builtin_amdgcn_s_setprio(1);
#pragma unroll 2
        for (int kk = 0; kk < 6; ++kk) {
            bf16x8 bo[4], awp[2];
#pragma unroll
            for (int cn = 0; cn < 4; ++cn)
                bo[cn] = *(const bf16x8*)&xb[(cn * 16 + li) * XSTR + kk * 32 + gi * 8];
#pragma unroll
            for (int ct = 0; ct < 2; ++ct)
                awp[ct] = *(const bf16x8*)&projT[(size_t)((2 * w + ct) * 16 + li) * 192 + kk * 32 + gi * 8];
#pragma unroll
            for (int ct = 0; ct < 2; ++ct)
#pragma unroll
                for (int cn = 0; cn < 4; ++cn)
                    pa[ct][cn] = __builtin_amdgcn_mfma_f32_16x16x32_bf16(awp[ct], bo[cn], pa[ct][cn], 0, 0, 0);
        }
        __builtin_amdgcn_s_setprio(0);

        // ======== in-register transpose + FULL-128B-LINE stores ========
        // store instr (cn,h): lane L -> token 16cn+8h+(L>>3), f32x4-col 8w+(L&7).
        // value from pa[(L&7)>>2][cn], src lane 8h+(L>>3)+16*(L&3).
        {
            const int L = tid & 63;
            f32x4* og = (f32x4*)(outg + (size_t)win * 12288);
#pragma unroll
            for (int cn = 0; cn < 4; ++cn)
#pragma unroll
                for (int h = 0; h < 2; ++h) {
                    const int sl = 8 * h + (L >> 3) + 16 * (L & 3);
                    f32x4 y;
#pragma unroll
                    for (int e = 0; e < 4; ++e) {
                        float v0 = __shfl(pa[0][cn][e], sl);
                        float v1 = __shfl(pa[1][cn][e], sl);
                        y[e] = (L & 4) ? v1 : v0;
                    }
                    og[(16 * cn + 8 * h + (L >> 3)) * 48 + 8 * w + (L & 7)] = y;
                }
        }

        cur ^= 1;
    }
}

extern "C" void kernel_launch(void* const* d_in, const int* in_sizes, int n_in,
                              void* d_out, int out_size, void* d_ws, size_t ws_size,
                              hipStream_t stream)
{
    const float* x          = (const float*)d_in[0];
    const float* wq         = (const float*)d_in[1];
    const float* bq         = (const float*)d_in[2];
    const float* wkv        = (const float*)d_in[3];
    const float* bkv        = (const float*)d_in[4];
    const float* bias_table = (const float*)d_in[5];
    const float* proj_w     = (const float*)d_in[6];
    const float* proj_b     = (const float*)d_in[7];
    float* out = (float*)d_out;

    int B = in_sizes[0] / (64 * 192);

    bf16*  wqkvT = (bf16*)d_ws;
    bf16*  projT = (bf16*)((char*)d_ws + 221184);
    float* biasB = (float*)((char*)d_ws + 294912);

    wattn_prep<<<672, 256, 0, stream>>>(wq, wkv, bias_table, proj_w, wqkvT, projT, biasB);

    wattn_main<<<(B + 1) / 2, 384, 0, stream>>>(x, wqkvT, bq, bkv, projT, biasB, proj_b, out, B);
}

// Round 10
// 246.419 us; speedup vs baseline: 2.0431x; 2.0431x over previous
//
#include <hip/hip_runtime.h>
#include <hip/hip_bf16.h>

typedef __bf16 bf16;
typedef bf16 bf16x8 __attribute__((ext_vector_type(8)));
typedef bf16 bf16x4 __attribute__((ext_vector_type(4)));
typedef short s16x4 __attribute__((ext_vector_type(4)));
typedef float f32x4 __attribute__((ext_vector_type(4)));

#define SCALE 0.17677669529663687f  // 1/sqrt(32)

// LDS: xb bf16 [64][208] @0 ; ob bf16 [64][208] @13312. 53,248 B -> up to 3 blocks/CU.
#define XSTR 208
#define XELEMS 13312
#define SMEM_ELEMS 26624

#if defined(__has_builtin)
#if __has_builtin(__builtin_amdgcn_mfma_f32_16x16x16bf16_1k)
#define HAS_MFMA16 1
#endif
#endif

// ---------------- prep kernel (unchanged, validated) ----------------
__global__ void wattn_prep(const float* __restrict__ wq, const float* __restrict__ wkv,
                           const float* __restrict__ bias_table, const float* __restrict__ proj_w,
                           bf16* __restrict__ wqkvT, bf16* __restrict__ projT,
                           float* __restrict__ biasB)
{
    int t = blockIdx.x * 256 + threadIdx.x;
    if (t < 110592) {                       // wqkvT[n][k] = W[k][n]
        int n = t / 192, k = t % 192;
        float v = (n < 192) ? wq[k * 192 + n] : wkv[k * 384 + (n - 192)];
        wqkvT[t] = (bf16)v;
    } else if (t < 147456) {                // projT[n][k] = proj_w[k][n]
        int e = t - 110592;
        int n = e / 192, k = e % 192;
        projT[e] = (bf16)proj_w[k * 192 + n];
    } else if (t < 172032) {                // biasB[h][m>>2][n][m&3]
        int e = t - 147456;
        int h  = e >> 12;
        int mb = (e >> 8) & 15;
        int n  = (e >> 2) & 63;
        int mr = e & 3;
        int m  = mb * 4 + mr;
        int idx = ((n & 7) - (m & 7) + 7) * 15 + ((n >> 3) - (m >> 3) + 7);
        biasB[e] = bias_table[idx * 6 + h];
    }
}

#if !defined(HAS_MFMA16)
// fallback: build K=32 frag from two D-layout bf16x4 tiles via shuffles
__device__ __forceinline__ bf16x8 build8(bf16x4 t0, bf16x4 t1, int li, int gi) {
    union { bf16x4 v; unsigned u[2]; } a0, a1;
    a0.v = t0; a1.v = t1;
    int b = li + 32 * (gi & 1);
    unsigned l0  = __shfl(a0.u[0], b),      l1  = __shfl(a0.u[1], b);
    unsigned l0h = __shfl(a0.u[0], b + 16), l1h = __shfl(a0.u[1], b + 16);
    unsigned h0  = __shfl(a1.u[0], b),      h1  = __shfl(a1.u[1], b);
    unsigned h0h = __shfl(a1.u[0], b + 16), h1h = __shfl(a1.u[1], b + 16);
    bool hi = (gi & 2);
    union { bf16x8 v8; unsigned u[4]; } r;
    r.u[0] = hi ? h0 : l0;   r.u[1] = hi ? h1 : l1;
    r.u[2] = hi ? h0h : l0h; r.u[3] = hi ? h1h : l1h;
    return r.v8;
}
#endif

// ---------------- fused main kernel: one window per block, one head per wave ----------------
// stage -> B1 -> passA(q,k) -> QK^T -> softmax -> passB(v) -> PV -> attn-out to ob ->
// B2 -> proj -> in-register transpose -> FULL-128B-LINE stores.   2 barriers, 53.2 KB LDS.
__global__ __launch_bounds__(384, 4)
void wattn_main(const float* __restrict__ x, const bf16* __restrict__ wqkvT,
                const float* __restrict__ bq, const float* __restrict__ bkv,
                const bf16* __restrict__ projT, const float* __restrict__ biasB,
                const float* __restrict__ proj_b, float* __restrict__ outg)
{
    __shared__ __align__(16) bf16 smem[SMEM_ELEMS];
    const int tid = threadIdx.x;
    const int li  = tid & 15;
    const int gi  = (tid >> 4) & 3;
    const int w   = tid >> 6;        // wave = head, 0..5
    const int win = blockIdx.x;

    bf16* xb = smem;
    bf16* ob = smem + XELEMS;
    const int srow = tid / 48, scol = tid % 48;
    const f32x4 fz = {0.f, 0.f, 0.f, 0.f};

    // ---- stage x: f32 global -> bf16 LDS [64][208] ----
    {
        const float4* xg = (const float4*)(x + (size_t)win * 12288);
#pragma unroll
        for (int i = 0; i < 8; ++i) {
            float4 p = xg[(srow + 8 * i) * 48 + scol];
            bf16x4 v; v[0]=(bf16)p.x; v[1]=(bf16)p.y; v[2]=(bf16)p.z; v[3]=(bf16)p.w;
            *(bf16x4*)&xb[(srow + 8 * i) * XSTR + scol * 4] = v;
        }
    }
    __syncthreads();                                     // B1

    // ======== pass A: q,k via TRANSPOSED GEMM; bias as accumulator C-init ========
    bf16x4 qf[2][4], kf[2][4];
    {
        f32x4 bjq0 = *(const f32x4*)&bq [32 * w + 4 * gi];
        f32x4 bjq1 = *(const f32x4*)&bq [32 * w + 16 + 4 * gi];
        f32x4 bjk0 = *(const f32x4*)&bkv[32 * w + 4 * gi];
        f32x4 bjk1 = *(const f32x4*)&bkv[32 * w + 16 + 4 * gi];
        f32x4 aqk[4][4];
#pragma unroll
        for (int c = 0; c < 4; ++c) {
            aqk[0][c] = bjq0; aqk[1][c] = bjq1;
            aqk[2][c] = bjk0; aqk[3][c] = bjk1;
        }
#pragma unroll 2
        for (int kk = 0; kk < 6; ++kk) {
            bf16x8 bx[4], aw[4];
#pragma unroll
            for (int c = 0; c < 4; ++c)
                bx[c] = *(const bf16x8*)&xb[(c * 16 + li) * XSTR + kk * 32 + gi * 8];
#pragma unroll
            for (int j = 0; j < 4; ++j) {
                int T = (j < 2) ? (2 * w + j) : (12 + 2 * w + (j - 2));
                aw[j] = *(const bf16x8*)&wqkvT[(size_t)(T * 16 + li) * 192 + kk * 32 + gi * 8];
            }
#pragma unroll
            for (int j = 0; j < 4; ++j)
#pragma unroll
                for (int c = 0; c < 4; ++c)
                    aqk[j][c] = __builtin_amdgcn_mfma_f32_16x16x32_bf16(aw[j], bx[c], aqk[j][c], 0, 0, 0);
        }
        // epilogue A: leaky (+SCALE for q) -> registers
#pragma unroll
        for (int j = 0; j < 2; ++j)
#pragma unroll
            for (int c = 0; c < 4; ++c) {
                bf16x4 rq, rk;
#pragma unroll
                for (int rg = 0; rg < 4; ++rg) {
                    float tq = aqk[j][c][rg];
                    float tk = aqk[2 + j][c][rg];
                    rq[rg] = (bf16)(fmaxf(tq, 0.2f * tq) * SCALE);
                    rk[rg] = (bf16)(fmaxf(tk, 0.2f * tk));
                }
                qf[j][c] = rq;
                kf[j][c] = rk;
            }
    }

    // ======== QK^T from registers, rel-pos-bias as accumulator C-init ========
    f32x4 s[4][4];
#pragma unroll
    for (int cm = 0; cm < 4; ++cm)
#pragma unroll
        for (int cn = 0; cn < 4; ++cn) {
            f32x4 bv = *(const f32x4*)&biasB[w * 4096 + (4 * cm + gi) * 256 + (16 * cn + li) * 4];
#if defined(HAS_MFMA16)
            f32x4 t = __builtin_amdgcn_mfma_f32_16x16x16bf16_1k(
                __builtin_bit_cast(s16x4, kf[0][cm]), __builtin_bit_cast(s16x4, qf[0][cn]), bv, 0, 0, 0);
            s[cm][cn] = __builtin_amdgcn_mfma_f32_16x16x16bf16_1k(
                __builtin_bit_cast(s16x4, kf[1][cm]), __builtin_bit_cast(s16x4, qf[1][cn]), t, 0, 0, 0);
#else
            s[cm][cn] = __builtin_amdgcn_mfma_f32_16x16x32_bf16(
                build8(kf[0][cm], kf[1][cm], li, gi), build8(qf[0][cn], qf[1][cn], li, gi), bv, 0, 0, 0);
#endif
        }

    // ======== softmax over keys; s dies into pb ========
    float rs[4];
    bf16x4 pb[4][4];
#pragma unroll
    for (int cn = 0; cn < 4; ++cn) {
        float m_ = -1e30f;
#pragma unroll
        for (int cm = 0; cm < 4; ++cm)
#pragma unroll
            for (int rg = 0; rg < 4; ++rg) m_ = fmaxf(m_, s[cm][cn][rg]);
        m_ = fmaxf(m_, __shfl_xor(m_, 16));
        m_ = fmaxf(m_, __shfl_xor(m_, 32));
        float ss = 0.f;
#pragma unroll
        for (int cm = 0; cm < 4; ++cm) {
            bf16x4 r;
#pragma unroll
            for (int rg = 0; rg < 4; ++rg) {
                float p = __expf(s[cm][cn][rg] - m_);
                ss += p;
                r[rg] = (bf16)p;
            }
            pb[cm][cn] = r;
        }
        ss += __shfl_xor(ss, 16);
        ss += __shfl_xor(ss, 32);
        rs[cn] = 1.f / ss;
    }

    // ======== pass B: v via NORMAL GEMM; bias as accumulator C-init ========
    bf16x4 vf[2][4];   // [d-half][m-subtile]
    {
        f32x4 bjv0 = *(const f32x4*)&bkv[192 + 32 * w + 4 * gi];
        f32x4 bjv1 = *(const f32x4*)&bkv[192 + 32 * w + 16 + 4 * gi];
        f32x4 av_[4][2];
#pragma unroll
        for (int rt = 0; rt < 4; ++rt) { av_[rt][0] = bjv0; av_[rt][1] = bjv1; }
#pragma unroll 2
        for (int kk = 0; kk < 6; ++kk) {
            bf16x8 a[4], bwv[2];
#pragma unroll
            for (int rt = 0; rt < 4; ++rt)
                a[rt] = *(const bf16x8*)&xb[(rt * 16 + li) * XSTR + kk * 32 + gi * 8];
#pragma unroll
            for (int j = 0; j < 2; ++j)
                bwv[j] = *(const bf16x8*)&wqkvT[(size_t)((24 + 2 * w + j) * 16 + li) * 192 + kk * 32 + gi * 8];
#pragma unroll
            for (int rt = 0; rt < 4; ++rt)
#pragma unroll
                for (int j = 0; j < 2; ++j)
                    av_[rt][j] = __builtin_amdgcn_mfma_f32_16x16x32_bf16(a[rt], bwv[j], av_[rt][j], 0, 0, 0);
        }
#pragma unroll
        for (int j = 0; j < 2; ++j)
#pragma unroll
            for (int rt = 0; rt < 4; ++rt) {
                bf16x4 r;
#pragma unroll
                for (int rg = 0; rg < 4; ++rg) {
                    float t = av_[rt][j][rg];
                    r[rg] = (bf16)(fmaxf(t, 0.2f * t));
                }
                vf[j][rt] = r;
            }
    }

    // ======== PV entirely from registers; normalized attn-out -> ob (no barrier needed) ====
#pragma unroll
    for (int ct = 0; ct < 2; ++ct)
#pragma unroll
        for (int cn = 0; cn < 4; ++cn) {
#if defined(HAS_MFMA16)
            f32x4 t = fz;
#pragma unroll
            for (int rt = 0; rt < 4; ++rt)
                t = __builtin_amdgcn_mfma_f32_16x16x16bf16_1k(
                        __builtin_bit_cast(s16x4, vf[ct][rt]),
                        __builtin_bit_cast(s16x4, pb[rt][cn]), t, 0, 0, 0);
#else
            f32x4 t = fz;
#pragma unroll
            for (int c = 0; c < 2; ++c)
                t = __builtin_amdgcn_mfma_f32_16x16x32_bf16(
                        build8(vf[ct][2 * c], vf[ct][2 * c + 1], li, gi),
                        build8(pb[2 * c][cn], pb[2 * c + 1][cn], li, gi), t, 0, 0, 0);
#endif
            bf16x4 r;
#pragma unroll
            for (int rg = 0; rg < 4; ++rg) r[rg] = (bf16)(t[rg] * rs[cn]);
            *(bf16x4*)&ob[(cn * 16 + li) * XSTR + 32 * w + 16 * ct + 4 * gi] = r;
        }
    __syncthreads();                                     // B2 (attn-out complete)

    // ======== proj (transposed); proj_b as accumulator C-init ========
    f32x4 pa[2][4];
    {
        f32x4 pb0 = *(const f32x4*)&proj_b[32 * w + 4 * gi];
        f32x4 pb1 = *(const f32x4*)&proj_b[32 * w + 16 + 4 * gi];
#pragma unroll
        for (int cn = 0; cn < 4; ++cn) { pa[0][cn] = pb0; pa[1][cn] = pb1; }
    }
#pragma unroll 2
    for (int kk = 0; kk < 6; ++kk) {
        bf16x8 bo[4], awp[2];
#pragma unroll
        for (int cn = 0; cn < 4; ++cn)
            bo[cn] = *(const bf16x8*)&ob[(cn * 16 + li) * XSTR + kk * 32 + gi * 8];
#pragma unroll
        for (int ct = 0; ct < 2; ++ct)
            awp[ct] = *(const bf16x8*)&projT[(size_t)((2 * w + ct) * 16 + li) * 192 + kk * 32 + gi * 8];
#pragma unroll
        for (int ct = 0; ct < 2; ++ct)
#pragma unroll
            for (int cn = 0; cn < 4; ++cn)
                pa[ct][cn] = __builtin_amdgcn_mfma_f32_16x16x32_bf16(awp[ct], bo[cn], pa[ct][cn], 0, 0, 0);
    }

    // ======== in-register transpose + FULL-128B-LINE stores (verified mapping, R9) ========
    // store instr (cn,h): lane L -> token 16cn+8h+(L>>3), f32x4-col 8w+(L&7).
    // value from pa[(L&4)?1:0][cn], src lane 8h+(L>>3)+16*(L&3).
    {
        const int L = tid & 63;
        f32x4* og = (f32x4*)(outg + (size_t)win * 12288);
#pragma unroll
        for (int cn = 0; cn < 4; ++cn)
#pragma unroll
            for (int h = 0; h < 2; ++h) {
                const int sl = 8 * h + (L >> 3) + 16 * (L & 3);
                f32x4 y;
#pragma unroll
                for (int e = 0; e < 4; ++e) {
                    float v0 = __shfl(pa[0][cn][e], sl);
                    float v1 = __shfl(pa[1][cn][e], sl);
                    y[e] = (L & 4) ? v1 : v0;
                }
                og[(16 * cn + 8 * h + (L >> 3)) * 48 + 8 * w + (L & 7)] = y;
            }
    }
}

extern "C" void kernel_launch(void* const* d_in, const int* in_sizes, int n_in,
                              void* d_out, int out_size, void* d_ws, size_t ws_size,
                              hipStream_t stream)
{
    const float* x          = (const float*)d_in[0];
    const float* wq         = (const float*)d_in[1];
    const float* bq         = (const float*)d_in[2];
    const float* wkv        = (const float*)d_in[3];
    const float* bkv        = (const float*)d_in[4];
    const float* bias_table = (const float*)d_in[5];
    const float* proj_w     = (const float*)d_in[6];
    const float* proj_b     = (const float*)d_in[7];
    float* out = (float*)d_out;

    int B = in_sizes[0] / (64 * 192);

    bf16*  wqkvT = (bf16*)d_ws;
    bf16*  projT = (bf16*)((char*)d_ws + 221184);
    float* biasB = (float*)((char*)d_ws + 294912);

    wattn_prep<<<672, 256, 0, stream>>>(wq, wkv, bias_table, proj_w, wqkvT, projT, biasB);

    wattn_main<<<B, 384, 0, stream>>>(x, wqkvT, bq, bkv, projT, biasB, proj_b, out);
}